// Round 1
// baseline (774.397 us; speedup 1.0000x reference)
//
#include <hip/hip_runtime.h>

#define NN 10000
#define EE 160000
#define BB 4
#define TTT 12
#define FFF 16
#define CCC 64
#define BT 48      // BB*TTT
#define NF 768     // BT*FFF

// workspace byte offsets (256B aligned)
#define WS_DEG     0u
#define WS_OFFS    40960u
#define WS_CURS    81920u
#define WS_TWT     122880u           // 12288 floats
#define WS_RWT     172032u           // 1024 floats
#define WS_CSR     176128u           // 160000 ints
#define WS_V       816128u           // 7,680,000 floats
#define WS_TX1     31536128u         // 7,680,000 floats  (ends ~62.3 MB)

__global__ void k_count(const int* __restrict__ ei, float* deg, int* cnt){
    int e = blockIdx.x * 256 + threadIdx.x;
    if (e < EE){
        int r = ei[e];
        int c = ei[EE + e];
        atomicAdd(&deg[r], 1.0f);
        atomicAdd(&cnt[c], 1);
    }
}

// single-block scan over N=10000 (cnt may alias curs; safe: each index read before written)
__global__ void k_scan(const int* cnt, int* offs, int* curs){
    __shared__ int buf[1024];
    __shared__ int carry;
    int tid = threadIdx.x;
    if (tid == 0) carry = 0;
    __syncthreads();
    for (int base = 0; base < NN; base += 1024){
        int i = base + tid;
        int x = (i < NN) ? cnt[i] : 0;
        buf[tid] = x;
        __syncthreads();
        for (int off = 1; off < 1024; off <<= 1){
            int t = (tid >= off) ? buf[tid - off] : 0;
            __syncthreads();
            buf[tid] += t;
            __syncthreads();
        }
        int excl = buf[tid] - x;
        if (i < NN){ offs[i] = carry + excl; curs[i] = carry + excl; }
        __syncthreads();
        if (tid == 0) carry += buf[1023];
        __syncthreads();
    }
    if (tid == 0) offs[NN] = carry;
}

__global__ void k_fill(const int* __restrict__ ei, int* curs, int* __restrict__ csr){
    int e = blockIdx.x * 256 + threadIdx.x;
    if (e < EE){
        int c = ei[EE + e];
        int pos = atomicAdd(&curs[c], 1);
        csr[pos] = ei[e];   // source node (row)
    }
}

// v[n][b*12+t][f] = x[b][n][f][t] ; per-(b,n) 192-float LDS transpose
__global__ void k_buildv(const float* __restrict__ x, float* __restrict__ v){
    __shared__ float s[192];
    int n = blockIdx.x / BB;
    int b = blockIdx.x % BB;
    int tid = threadIdx.x;                       // tid = f*12 + t
    float val = x[(size_t)(b * NN + n) * 192 + tid];
    s[(tid % 12) * 16 + (tid / 12)] = val;       // -> [t][f]
    __syncthreads();
    v[(size_t)n * NF + b * 192 + tid] = s[tid];
}

// transpose weights for coalesced per-lane-o access
__global__ void k_wt(const float* __restrict__ tW, const float* __restrict__ rW,
                     float* __restrict__ tWt, float* __restrict__ rWt){
    int idx = blockIdx.x * 256 + threadIdx.x;
    if (idx < CCC * CCC * 3){
        int o = idx & 63; int r = idx >> 6; int k = r % 3; int c = r / 3;
        tWt[idx] = tW[(o * 64 + c) * 3 + k];     // tWt[(c*3+k)*64+o]
    } else if (idx < CCC * CCC * 3 + FFF * CCC){
        int j = idx - CCC * CCC * 3;
        int o = j & 63; int f = j >> 6;
        rWt[j] = rW[o * 16 + f];                 // rWt[f*64+o]
    }
}

// Tx1 = (2/lam)*(deg*v - agg) - v ; agg via CSR gather (no atomics)
__global__ void k_lhat(const float* __restrict__ v, const float* __restrict__ deg,
                       const int* __restrict__ offs, const int* __restrict__ csr,
                       const float* __restrict__ lam, float* __restrict__ tx1){
    int n = blockIdx.x;
    int tid = threadIdx.x;
    float s2 = 2.0f / lam[0];
    float dn = deg[n];
    int beg = offs[n], end = offs[n + 1];
    float a0 = 0.f, a1 = 0.f, a2 = 0.f;
    for (int j = beg; j < end; ++j){
        const float* p = v + (size_t)csr[j] * NF;
        a0 += p[tid]; a1 += p[tid + 256]; a2 += p[tid + 512];
    }
    const float* pv = v + (size_t)n * NF;
    float v0 = pv[tid], v1 = pv[tid + 256], v2 = pv[tid + 512];
    float* po = tx1 + (size_t)n * NF;
    po[tid]       = s2 * (dn * v0 - a0) - v0;
    po[tid + 256] = s2 * (dn * v1 - a1) - v1;
    po[tid + 512] = s2 * (dn * v2 - a2) - v2;
}

// per-node: Tx2 + Cheb GEMM + relu -> sp(LDS) -> temporal conv + residual + relu + LN -> out
__global__ __launch_bounds__(256) void k_fused(
    const float* __restrict__ v, const float* __restrict__ tx1,
    const float* __restrict__ deg, const int* __restrict__ offs, const int* __restrict__ csr,
    const float* __restrict__ lam,
    const float* __restrict__ chebW, const float* __restrict__ chebB,
    const float* __restrict__ tWt, const float* __restrict__ timeB,
    const float* __restrict__ rWt, const float* __restrict__ resB,
    const float* __restrict__ gamma, const float* __restrict__ beta,
    float* __restrict__ out)
{
    __shared__ float T0[NF], T1[NF], T2[NF];
    __shared__ float sp[BT * CCC];
    __shared__ float ldsW[16 * 3 * 64];

    int n = blockIdx.x;
    int tid = threadIdx.x;
    float s2 = 2.0f / lam[0];
    float dn = deg[n];

    // ---- build T0/T1/T2 in LDS (elements tid, tid+256, tid+512) ----
    const float* pv = v   + (size_t)n * NF;
    const float* p1 = tx1 + (size_t)n * NF;
    float v0 = pv[tid], v1 = pv[tid + 256], v2 = pv[tid + 512];
    float u0 = p1[tid], u1 = p1[tid + 256], u2 = p1[tid + 512];
    float a0 = 0.f, a1 = 0.f, a2 = 0.f;
    int beg = offs[n], end = offs[n + 1];
    for (int j = beg; j < end; ++j){
        const float* p = tx1 + (size_t)csr[j] * NF;
        a0 += p[tid]; a1 += p[tid + 256]; a2 += p[tid + 512];
    }
    T0[tid] = v0;       T0[tid + 256] = v1;  T0[tid + 512] = v2;
    T1[tid] = u0;       T1[tid + 256] = u1;  T1[tid + 512] = u2;
    T2[tid]       = 2.0f * (s2 * (dn * u0 - a0) - u0) - v0;
    T2[tid + 256] = 2.0f * (s2 * (dn * u1 - a1) - u1) - v1;
    T2[tid + 512] = 2.0f * (s2 * (dn * u2 - a2) - u2) - v2;
    __syncthreads();

    int g = tid >> 6;      // b  (== wave id)
    int c = tid & 63;      // lane: c for Cheb GEMM, o for temporal conv

    // ---- Chebyshev GEMM: sp[bt][c] = relu(b[c] + sum_f T_k[bt][f]*W_k[f][c]) ----
    float so[12];
    float cb = chebB[c];
    #pragma unroll
    for (int j = 0; j < 12; ++j) so[j] = cb;
    #pragma unroll 4
    for (int f = 0; f < 16; ++f){
        float w0 = chebW[f * 64 + c];
        float w1 = chebW[1024 + f * 64 + c];
        float w2 = chebW[2048 + f * 64 + c];
        #pragma unroll
        for (int j = 0; j < 12; ++j){
            int bt = g * 12 + j;
            so[j] += T0[bt * 16 + f] * w0;
            so[j] += T1[bt * 16 + f] * w1;
            so[j] += T2[bt * 16 + f] * w2;
        }
    }
    #pragma unroll
    for (int j = 0; j < 12; ++j) sp[(g * 12 + j) * 64 + c] = fmaxf(so[j], 0.0f);
    // sp rows of wave g are written and read only by wave g; syncs below are for ldsW

    // ---- temporal conv + residual ----
    int o = c;
    float acc[12];
    float ib = timeB[o] + resB[o];
    #pragma unroll
    for (int t = 0; t < 12; ++t) acc[t] = ib;

    // residual: sum_f x[b,n,f,t]*resW[o,f] via T0
    #pragma unroll 4
    for (int f = 0; f < 16; ++f){
        float w = rWt[f * 64 + o];
        #pragma unroll
        for (int t = 0; t < 12; ++t) acc[t] += T0[(g * 12 + t) * 16 + f] * w;
    }

    // temporal conv: 4 chunks of 16 channels, weights staged [dc][k][o] in LDS
    for (int ch = 0; ch < 4; ++ch){
        __syncthreads();
        #pragma unroll
        for (int i = 0; i < 12; ++i){
            int idx = i * 256 + tid;
            ldsW[idx] = tWt[ch * 3072 + idx];
        }
        __syncthreads();
        #pragma unroll 2
        for (int dc = 0; dc < 16; ++dc){
            float spv[12];
            #pragma unroll
            for (int t = 0; t < 12; ++t) spv[t] = sp[(g * 12 + t) * 64 + ch * 16 + dc];
            #pragma unroll
            for (int k = 0; k < 3; ++k){
                float w = ldsW[(dc * 3 + k) * 64 + o];
                #pragma unroll
                for (int t = 0; t < 12; ++t){
                    int tt = t + k - 1;
                    if (tt >= 0 && tt < 12) acc[t] += spv[tt] * w;
                }
            }
        }
    }

    // ---- relu + LayerNorm over o (64 lanes == one wave, b fixed per wave) ----
    float gam = gamma[o], bet = beta[o];
    float res[12];
    #pragma unroll
    for (int t = 0; t < 12; ++t){
        float h = fmaxf(acc[t], 0.0f);
        float s = h, q = h * h;
        #pragma unroll
        for (int off = 32; off > 0; off >>= 1){
            s += __shfl_xor(s, off);
            q += __shfl_xor(q, off);
        }
        float mu  = s * (1.0f / 64.0f);
        float var = q * (1.0f / 64.0f) - mu * mu;
        float r   = rsqrtf(var + 1e-5f);
        res[t] = (h - mu) * r * gam + bet;
    }
    // out[((b*N+n)*64+o)*12 + t], 48B-aligned -> 3x float4
    size_t obase = ((size_t)(g * NN + n) * CCC + o) * TTT;
    float4* op = (float4*)(out + obase);
    op[0] = make_float4(res[0], res[1], res[2],  res[3]);
    op[1] = make_float4(res[4], res[5], res[6],  res[7]);
    op[2] = make_float4(res[8], res[9], res[10], res[11]);
}

extern "C" void kernel_launch(void* const* d_in, const int* in_sizes, int n_in,
                              void* d_out, int out_size, void* d_ws, size_t ws_size,
                              hipStream_t stream)
{
    (void)in_sizes; (void)n_in; (void)out_size; (void)ws_size;
    const float* x   = (const float*)d_in[0];
    const int*   ei  = (const int*)  d_in[1];
    const float* lam = (const float*)d_in[2];
    const float* chW = (const float*)d_in[3];
    const float* chB = (const float*)d_in[4];
    const float* tW  = (const float*)d_in[5];
    const float* tB  = (const float*)d_in[6];
    const float* rW  = (const float*)d_in[7];
    const float* rB  = (const float*)d_in[8];
    const float* gam = (const float*)d_in[9];
    const float* bet = (const float*)d_in[10];
    float* out = (float*)d_out;

    char* ws = (char*)d_ws;
    float* deg  = (float*)(ws + WS_DEG);
    int*   offs = (int*)  (ws + WS_OFFS);
    int*   curs = (int*)  (ws + WS_CURS);
    float* tWt  = (float*)(ws + WS_TWT);
    float* rWt  = (float*)(ws + WS_RWT);
    int*   csr  = (int*)  (ws + WS_CSR);
    float* v    = (float*)(ws + WS_V);
    float* tx1  = (float*)(ws + WS_TX1);

    hipMemsetAsync(ws, 0, WS_TWT, stream);               // zero deg/offs/curs
    k_count<<<(EE + 255) / 256, 256, 0, stream>>>(ei, deg, curs);
    k_scan <<<1, 1024, 0, stream>>>(curs, offs, curs);
    k_fill <<<(EE + 255) / 256, 256, 0, stream>>>(ei, curs, csr);
    k_buildv<<<NN * BB, 192, 0, stream>>>(x, v);
    k_wt   <<<52, 256, 0, stream>>>(tW, rW, tWt, rWt);
    k_lhat <<<NN, 256, 0, stream>>>(v, deg, offs, csr, lam, tx1);
    k_fused<<<NN, 256, 0, stream>>>(v, tx1, deg, offs, csr, lam,
                                    chW, chB, tWt, tB, rWt, rB, gam, bet, out);
}